// Round 9
// baseline (414.727 us; speedup 1.0000x reference)
//
#include <hip/hip_runtime.h>
#include <hip/hip_bf16.h>
#include <stdint.h>

#define T_TOK 1024
#define HID   1024
#define INT_  4096
#define NE    8

typedef __attribute__((ext_vector_type(4))) float f32x4;
typedef __attribute__((ext_vector_type(8))) short short8;

__device__ int g_tok[NE][T_TOK];
__device__ int g_cnt[NE];

__device__ __forceinline__ uint32_t pack2bf(float a, float b) {
  unsigned short ua = __builtin_bit_cast(unsigned short, (__bf16)a);
  unsigned short ub = __builtin_bit_cast(unsigned short, (__bf16)b);
  return (uint32_t)ua | ((uint32_t)ub << 16);
}

// global_load_lds: per-lane global src, wave-uniform LDS base (HW adds lane*16)
#define GL16(gsrc, ldst)                                                       \
  __builtin_amdgcn_global_load_lds(                                            \
      (const __attribute__((address_space(1))) void*)(gsrc),                   \
      (__attribute__((address_space(3))) void*)(ldst), 16, 0, 0)

// build bf16 B-fragment (8 k-elems, fixed n) from f32 [k][128] LDS tile
__device__ __forceinline__ short8 bcol(const float* __restrict__ b32, int n, int ke) {
  uint4 u;
  u.x = pack2bf(b32[(ke + 0) * 128 + n], b32[(ke + 1) * 128 + n]);
  u.y = pack2bf(b32[(ke + 2) * 128 + n], b32[(ke + 3) * 128 + n]);
  u.z = pack2bf(b32[(ke + 4) * 128 + n], b32[(ke + 5) * 128 + n]);
  u.w = pack2bf(b32[(ke + 6) * 128 + n], b32[(ke + 7) * 128 + n]);
  return __builtin_bit_cast(short8, u);
}

// ---------------- Kernel 0: per-expert token compaction ---------------------
__global__ void k0_compact(const int* __restrict__ mask)  // [T_TOK][NE]
{
  const int w    = threadIdx.x >> 6;
  const int lane = threadIdx.x & 63;
  if (w >= NE) return;
  const unsigned long long ltmask = (1ull << lane) - 1ull;
  int base = 0;
  #pragma unroll
  for (int c = 0; c < T_TOK / 64; ++c) {
    const int t = c * 64 + lane;
    const bool pred = mask[t * NE + w] != 0;
    const unsigned long long bal = __ballot(pred);
    if (pred) g_tok[w][base + __popcll(bal & ltmask)] = t;
    base += __popcll(bal);
  }
  if (lane == 0) g_cnt[w] = base;
}

// ---------------- Kernel 1: act[e,slot,i] = up * silu(gate) -----------------
// grid (INT_/128, T_TOK/128, NE), 512 threads (8 waves, 2m x 4n).
// B (gate,up) staged f32 via global_load_lds (linear [k][n]); cvt on read.
// A reg-staged bf16 with XOR swizzle (x is L2-resident, cheap).
// act written with column swizzle baked in (for k2's DMA-linear A staging).
__global__ __launch_bounds__(512, 1)
void k1_gateup(const float* __restrict__ x,        // [T_TOK][HID]
               const float* __restrict__ wgu,      // [NE][HID][2*INT_]
               unsigned short* __restrict__ act)   // [NE][T_TOK][INT_] bf16, col-swizzled
{
  const int e   = blockIdx.z;
  const int cnt = g_cnt[e];
  const int mt  = blockIdx.y;
  const int t0  = mt * 128;
  if (t0 >= cnt) return;

  __shared__ char  sA[128 * 64 * 2];   // bf16 [m][k] swizzled (16 KB)
  __shared__ float sBg[64 * 128];      // f32 [k][n] linear (32 KB)
  __shared__ float sBu[64 * 128];      // (32 KB)

  const int nt   = blockIdx.x;
  const int tid  = threadIdx.x;
  const int lane = tid & 63;
  const int wv   = tid >> 6;           // 0..7
  const int wm   = (wv >> 2) * 64;     // 0/64
  const int wn   = (wv & 3) * 32;      // 0/32/64/96

  const float* wb = wgu + (size_t)e * HID * (2 * INT_);
  const int n0 = nt * 128;

  f32x4 accg[4][2], accu[4][2];
  #pragma unroll
  for (int i = 0; i < 4; ++i)
    #pragma unroll
    for (int j = 0; j < 2; ++j) {
      accg[i][j] = (f32x4){0.f, 0.f, 0.f, 0.f};
      accu[i][j] = (f32x4){0.f, 0.f, 0.f, 0.f};
    }

  const int a_m = tid >> 4;            // 0..31
  const int a_k = (tid & 15) * 4;      // 0..60
  int tokr[4];
  #pragma unroll
  for (int p = 0; p < 4; ++p) tokr[p] = g_tok[e][t0 + p * 32 + a_m];

  // B DMA lane mapping: issue s covers k-rows [s*16, s*16+16); wave wv covers
  // rows s*16 + wv*2 + (lane>>5); 16B chunk (lane&31) within the 512B row.
  const int bkw = wv * 2;                       // wave-uniform row pair base
  const int bkl = (lane >> 5);                  // per-lane row select
  const int bnc = (lane & 31) * 4;              // per-lane n offset (f32)

  for (int kt = 0; kt < HID; kt += 64) {
    // ---- issue B DMAs (8 per thread: 4 gate + 4 up) — no VGPR round-trip
    #pragma unroll
    for (int s = 0; s < 4; ++s) {
      const int krow = s * 16 + bkw;            // wave-uniform
      const float* sg = wb + (size_t)(kt + krow + bkl) * (2 * INT_) + n0 + bnc;
      GL16(sg,         (char*)sBg + krow * 512);
      GL16(sg + INT_,  (char*)sBu + krow * 512);
    }
    // ---- stage A: gathered x rows [128][64] f32 -> bf16 LDS (swizzled)
    #pragma unroll
    for (int p = 0; p < 4; ++p) {
      const int m = p * 32 + a_m;
      f32x4 v = *(const f32x4*)(x + (size_t)tokr[p] * HID + kt + a_k);
      uint2 w; w.x = pack2bf(v[0], v[1]); w.y = pack2bf(v[2], v[3]);
      *(uint2*)(sA + m * 128 + ((a_k * 2) ^ ((m & 7) << 4))) = w;
    }
    __syncthreads();                            // drains vmcnt incl. DMA queue
    // ---- compute tile kt
    #pragma unroll
    for (int ks = 0; ks < 2; ++ks) {
      const int kfb = ks * 64 + ((lane >> 4) << 4);   // A byte offset
      const int ke  = ks * 32 + ((lane >> 4) << 3);   // B f32 k-base
      short8 af[4], bg[2], bu[2];
      #pragma unroll
      for (int i = 0; i < 4; ++i) {
        const int r = wm + i * 16 + (lane & 15);
        af[i] = *(const short8*)(sA + r * 128 + (kfb ^ ((r & 7) << 4)));
      }
      #pragma unroll
      for (int j = 0; j < 2; ++j) {
        const int n = wn + j * 16 + (lane & 15);
        bg[j] = bcol(sBg, n, ke);
        bu[j] = bcol(sBu, n, ke);
      }
      #pragma unroll
      for (int i = 0; i < 4; ++i)
        #pragma unroll
        for (int j = 0; j < 2; ++j) {
          accg[i][j] = __builtin_amdgcn_mfma_f32_16x16x32_bf16(af[i], bg[j], accg[i][j], 0, 0, 0);
          accu[i][j] = __builtin_amdgcn_mfma_f32_16x16x32_bf16(af[i], bu[j], accu[i][j], 0, 0, 0);
        }
    }
    __syncthreads();
  }

  // ---- epilogue: act = up * silu(gate), stored with col swizzle baked in
  unsigned short* ab = act + (size_t)e * T_TOK * INT_;
  #pragma unroll
  for (int i = 0; i < 4; ++i) {
    #pragma unroll
    for (int r = 0; r < 4; ++r) {
      const int slot = t0 + wm + i * 16 + ((lane >> 4) << 2) + r;
      if (slot < cnt) {
        #pragma unroll
        for (int j = 0; j < 2; ++j) {
          const int col = n0 + wn + j * 16 + (lane & 15);
          const int cw  = (col >> 3) & 7;
          const int colS = (col & ~56) | (((cw ^ (slot & 7)) & 7) << 3);
          const float g = accg[i][j][r];
          const float u = accu[i][j][r];
          const float s = u * g / (1.f + __expf(-g));
          ab[(size_t)slot * INT_ + colS] = __builtin_bit_cast(unsigned short, (__bf16)s);
        }
      }
    }
  }
}

// ---------------- Kernel 2: out[tok[slot],h] += act[e,slot] @ w_down[e] -----
// grid (HID/128, (T_TOK/128)*4, NE), 512 threads, K split 4-way.
// A (act bf16, pre-swizzled) AND B (wd f32) staged via global_load_lds.
__global__ __launch_bounds__(512, 1)
void k2_down(const unsigned short* __restrict__ act,  // col-swizzled bf16
             const float* __restrict__ wd,            // [NE][INT_][HID]
             float* __restrict__ out)                 // [T_TOK][HID]
{
  const int e   = blockIdx.z;
  const int cnt = g_cnt[e];
  const int mt  = blockIdx.y >> 2;
  const int ks4 = blockIdx.y & 3;
  const int t0  = mt * 128;
  if (t0 >= cnt) return;

  __shared__ char  sA[128 * 64 * 2];   // bf16 [m][k], swizzle baked by k1 (16 KB)
  __shared__ float sB[64 * 128];       // f32 [k][n] linear (32 KB)

  const int nt   = blockIdx.x;
  const int tid  = threadIdx.x;
  const int lane = tid & 63;
  const int wv   = tid >> 6;
  const int wm   = (wv >> 2) * 64;     // 0/64
  const int wn   = (wv & 3) * 32;      // 0/32/64/96

  const unsigned short* ab = act + (size_t)e * T_TOK * INT_;
  const float* wb = wd + (size_t)e * INT_ * HID;
  const int n0 = nt * 128;

  f32x4 acc[4][2];
  #pragma unroll
  for (int i = 0; i < 4; ++i)
    #pragma unroll
    for (int j = 0; j < 2; ++j) acc[i][j] = (f32x4){0.f, 0.f, 0.f, 0.f};

  const int bkw = wv * 2;
  const int bkl = (lane >> 5);
  const int bnc = (lane & 31) * 4;

  const int kbeg = ks4 * (INT_ / 4);
  const int kend = kbeg + (INT_ / 4);

  for (int kt = kbeg; kt < kend; kt += 64) {
    // ---- A DMA: 2 issues; wave wv covers rows s*64 + wv*8 + (lane>>3)
    #pragma unroll
    for (int s = 0; s < 2; ++s) {
      const int mrow = s * 64 + wv * 8;         // wave-uniform
      const unsigned short* srcA =
          ab + (size_t)(t0 + mrow + (lane >> 3)) * INT_ + kt + (lane & 7) * 8;
      GL16(srcA, (char*)sA + mrow * 128);
    }
    // ---- B DMA: 4 issues (as k1)
    #pragma unroll
    for (int s = 0; s < 4; ++s) {
      const int krow = s * 16 + bkw;
      const float* srcB = wb + (size_t)(kt + krow + bkl) * HID + n0 + bnc;
      GL16(srcB, (char*)sB + krow * 512);
    }
    __syncthreads();
    // ---- compute
    #pragma unroll
    for (int ks = 0; ks < 2; ++ks) {
      const int kfb = ks * 64 + ((lane >> 4) << 4);
      const int ke  = ks * 32 + ((lane >> 4) << 3);
      short8 af[4], bf[2];
      #pragma unroll
      for (int i = 0; i < 4; ++i) {
        const int r = wm + i * 16 + (lane & 15);
        af[i] = *(const short8*)(sA + r * 128 + (kfb ^ ((r & 7) << 4)));
      }
      #pragma unroll
      for (int j = 0; j < 2; ++j) {
        const int n = wn + j * 16 + (lane & 15);
        bf[j] = bcol(sB, n, ke);
      }
      #pragma unroll
      for (int i = 0; i < 4; ++i)
        #pragma unroll
        for (int j = 0; j < 2; ++j)
          acc[i][j] = __builtin_amdgcn_mfma_f32_16x16x32_bf16(af[i], bf[j], acc[i][j], 0, 0, 0);
    }
    __syncthreads();
  }

  // ---- epilogue: scatter-accumulate valid rows into out
  #pragma unroll
  for (int i = 0; i < 4; ++i) {
    #pragma unroll
    for (int r = 0; r < 4; ++r) {
      const int slot = t0 + wm + i * 16 + ((lane >> 4) << 2) + r;
      if (slot < cnt) {
        const int token = g_tok[e][slot];
        #pragma unroll
        for (int j = 0; j < 2; ++j) {
          const int col = n0 + wn + j * 16 + (lane & 15);
          atomicAdd(out + (size_t)token * HID + col, acc[i][j][r]);
        }
      }
    }
  }
}

extern "C" void kernel_launch(void* const* d_in, const int* in_sizes, int n_in,
                              void* d_out, int out_size, void* d_ws, size_t ws_size,
                              hipStream_t stream) {
  const float* x   = (const float*)d_in[0];
  const int*   idx = (const int*)d_in[1];
  const float* wgu = (const float*)d_in[2];
  const float* wd  = (const float*)d_in[3];
  float* out = (float*)d_out;
  unsigned short* act = (unsigned short*)d_ws;   // 64 MB

  hipMemsetAsync(d_out, 0, (size_t)out_size * sizeof(float), stream);

  k0_compact<<<1, 512, 0, stream>>>(idx);

  dim3 g1(INT_ / 128, T_TOK / 128, NE);        // (32, 8, 8)
  k1_gateup<<<g1, dim3(512), 0, stream>>>(x, wgu, act);

  dim3 g2(HID / 128, (T_TOK / 128) * 4, NE);   // (8, 32, 8) — y = mt*4|ks
  k2_down<<<g2, dim3(512), 0, stream>>>(act, wd, out);
}

// Round 10
// 366.419 us; speedup vs baseline: 1.1318x; 1.1318x over previous
//
#include <hip/hip_runtime.h>
#include <hip/hip_bf16.h>
#include <stdint.h>

#define T_TOK 1024
#define HID   1024
#define INT_  4096
#define NE    8

typedef __attribute__((ext_vector_type(4))) float f32x4;
typedef __attribute__((ext_vector_type(8))) short short8;

__device__ int g_tok[NE][T_TOK];
__device__ int g_cnt[NE];

__device__ __forceinline__ uint32_t pack2bf(float a, float b) {
  unsigned short ua = __builtin_bit_cast(unsigned short, (__bf16)a);
  unsigned short ub = __builtin_bit_cast(unsigned short, (__bf16)b);
  return (uint32_t)ua | ((uint32_t)ub << 16);
}

// global_load_lds: per-lane global src, wave-uniform LDS base (HW adds lane*16)
#define GL16(gsrc, ldst)                                                       \
  __builtin_amdgcn_global_load_lds(                                            \
      (const __attribute__((address_space(1))) void*)(gsrc),                   \
      (__attribute__((address_space(3))) void*)(ldst), 16, 0, 0)

// ---------------- Kernel 0: per-expert token compaction ---------------------
__global__ void k0_compact(const int* __restrict__ mask)  // [T_TOK][NE]
{
  const int w    = threadIdx.x >> 6;
  const int lane = threadIdx.x & 63;
  if (w >= NE) return;
  const unsigned long long ltmask = (1ull << lane) - 1ull;
  int base = 0;
  #pragma unroll
  for (int c = 0; c < T_TOK / 64; ++c) {
    const int t = c * 64 + lane;
    const bool pred = mask[t * NE + w] != 0;
    const unsigned long long bal = __ballot(pred);
    if (pred) g_tok[w][base + __popcll(bal & ltmask)] = t;
    base += __popcll(bal);
  }
  if (lane == 0) g_cnt[w] = base;
}

// ---------------- cvt_x: x f32 -> bf16 linear -------------------------------
__global__ void cvt_x(const float* __restrict__ xin, unsigned short* __restrict__ xout)
{
  const int i = (blockIdx.x * 256 + threadIdx.x) * 8;
  f32x4 a = *(const f32x4*)(xin + i);
  f32x4 b = *(const f32x4*)(xin + i + 4);
  uint4 u;
  u.x = pack2bf(a[0], a[1]); u.y = pack2bf(a[2], a[3]);
  u.z = pack2bf(b[0], b[1]); u.w = pack2bf(b[2], b[3]);
  *(uint4*)(xout + i) = u;
}

// ---------------- cvt_T: per-expert [R][C] f32 -> [C][R] bf16 ---------------
// 256 threads, 64x64 tile via LDS.
__global__ void cvt_T(const float* __restrict__ in, unsigned short* __restrict__ out,
                      int R, int C)
{
  __shared__ float tile[64][65];
  const int e  = blockIdx.z;
  const int c0 = blockIdx.x * 64;
  const int r0 = blockIdx.y * 64;
  const float*    ip = in  + (size_t)e * R * C;
  unsigned short* op = out + (size_t)e * R * C;
  const int t  = threadIdx.x;
  const int rr = t >> 4, c4 = (t & 15) * 4;
  #pragma unroll
  for (int s = 0; s < 4; ++s) {
    f32x4 v = *(const f32x4*)(ip + (size_t)(r0 + s * 16 + rr) * C + c0 + c4);
    tile[s * 16 + rr][c4 + 0] = v[0];
    tile[s * 16 + rr][c4 + 1] = v[1];
    tile[s * 16 + rr][c4 + 2] = v[2];
    tile[s * 16 + rr][c4 + 3] = v[3];
  }
  __syncthreads();
  const int c = t >> 2, rs = (t & 3) * 16;
  uint4 u0, u1;
  u0.x = pack2bf(tile[rs + 0][c],  tile[rs + 1][c]);
  u0.y = pack2bf(tile[rs + 2][c],  tile[rs + 3][c]);
  u0.z = pack2bf(tile[rs + 4][c],  tile[rs + 5][c]);
  u0.w = pack2bf(tile[rs + 6][c],  tile[rs + 7][c]);
  u1.x = pack2bf(tile[rs + 8][c],  tile[rs + 9][c]);
  u1.y = pack2bf(tile[rs + 10][c], tile[rs + 11][c]);
  u1.z = pack2bf(tile[rs + 12][c], tile[rs + 13][c]);
  u1.w = pack2bf(tile[rs + 14][c], tile[rs + 15][c]);
  unsigned short* orow = op + (size_t)(c0 + c) * R + r0 + rs;
  *(uint4*)(orow)     = u0;
  *(uint4*)(orow + 8) = u1;
}

// ---------------- Kernel 1: act[e,slot,i] = up * silu(gate) -----------------
// Pure-bf16 m97-style: both operands via global_load_lds (16B), source-XOR
// swizzle, zero staging VALU. 512 thr (8 waves, 2m x 4n), M=256 N=128(g+u).
__global__ __launch_bounds__(512, 1)
void k1_gateup(const unsigned short* __restrict__ xb,    // [T][H] bf16
               const unsigned short* __restrict__ wguT,  // [e][8192][1024] bf16
               unsigned short* __restrict__ act)         // [e][T][INT_] bf16 linear
{
  const int e   = blockIdx.z;
  const int cnt = g_cnt[e];
  const int mt  = blockIdx.y;
  const int t0  = mt * 256;
  if (t0 >= cnt) return;

  __shared__ char sA [256 * 128];      // [m][64k] bf16 (32 KB)
  __shared__ char sBg[128 * 128];      // [n][64k] bf16 (16 KB)
  __shared__ char sBu[128 * 128];      // (16 KB)

  const int nt   = blockIdx.x;
  const int tid  = threadIdx.x;
  const int lane = tid & 63;
  const int wv   = tid >> 6;           // 0..7
  const int wm   = (wv >> 2) * 128;    // 0/128
  const int wn   = (wv & 3) * 32;      // 0/32/64/96
  const int n0   = nt * 128;

  const unsigned short* wg = wguT + (size_t)e * 8192 * HID + (size_t)n0 * HID;
  const unsigned short* wu = wg + (size_t)4096 * HID;

  f32x4 accg[8][2], accu[8][2];
  #pragma unroll
  for (int i = 0; i < 8; ++i)
    #pragma unroll
    for (int j = 0; j < 2; ++j) {
      accg[i][j] = (f32x4){0.f, 0.f, 0.f, 0.f};
      accu[i][j] = (f32x4){0.f, 0.f, 0.f, 0.f};
    }

  // DMA lane mapping: row = base + lane/8, chunk slot = lane%8; source chunk
  // XOR-permuted by row&7 so reads can swizzle (rule #21, both-sides).
  const int drow  = lane >> 3;                    // 0..7
  const int dchk8 = (((lane & 7) ^ drow) << 3);   // bf16 elem offset of src chunk

  int tokA[4];
  #pragma unroll
  for (int s = 0; s < 4; ++s)
    tokA[s] = g_tok[e][t0 + (s * 8 + wv) * 8 + drow];

  for (int kt = 0; kt < HID; kt += 64) {
    #pragma unroll
    for (int s = 0; s < 4; ++s) {
      const int rb = (s * 8 + wv) * 8;            // wave-uniform, rows rb..rb+7
      GL16(xb + (size_t)tokA[s] * HID + kt + dchk8, sA + rb * 128);
    }
    #pragma unroll
    for (int s = 0; s < 2; ++s) {
      const int rb = (s * 8 + wv) * 8;
      GL16(wg + (size_t)(rb + drow) * HID + kt + dchk8, sBg + rb * 128);
      GL16(wu + (size_t)(rb + drow) * HID + kt + dchk8, sBu + rb * 128);
    }
    __syncthreads();                              // drains DMA queue
    #pragma unroll
    for (int ks = 0; ks < 2; ++ks) {
      const int kfb = ks * 64 + ((lane >> 4) << 4);
      short8 af[8], bg[2], bu[2];
      #pragma unroll
      for (int i = 0; i < 8; ++i) {
        const int r = wm + i * 16 + (lane & 15);
        af[i] = *(const short8*)(sA + r * 128 + (kfb ^ ((r & 7) << 4)));
      }
      #pragma unroll
      for (int j = 0; j < 2; ++j) {
        const int r = wn + j * 16 + (lane & 15);
        const int off = r * 128 + (kfb ^ ((r & 7) << 4));
        bg[j] = *(const short8*)(sBg + off);
        bu[j] = *(const short8*)(sBu + off);
      }
      #pragma unroll
      for (int i = 0; i < 8; ++i)
        #pragma unroll
        for (int j = 0; j < 2; ++j) {
          accg[i][j] = __builtin_amdgcn_mfma_f32_16x16x32_bf16(af[i], bg[j], accg[i][j], 0, 0, 0);
          accu[i][j] = __builtin_amdgcn_mfma_f32_16x16x32_bf16(af[i], bu[j], accu[i][j], 0, 0, 0);
        }
    }
    __syncthreads();
  }

  unsigned short* ab = act + (size_t)e * T_TOK * INT_;
  #pragma unroll
  for (int i = 0; i < 8; ++i) {
    #pragma unroll
    for (int r = 0; r < 4; ++r) {
      const int slot = t0 + wm + i * 16 + ((lane >> 4) << 2) + r;
      if (slot < cnt) {
        #pragma unroll
        for (int j = 0; j < 2; ++j) {
          const int col = n0 + wn + j * 16 + (lane & 15);
          const float g = accg[i][j][r];
          const float u = accu[i][j][r];
          const float s = u * g / (1.f + __expf(-g));
          ab[(size_t)slot * INT_ + col] = __builtin_bit_cast(unsigned short, (__bf16)s);
        }
      }
    }
  }
}

// ---------------- Kernel 2: out += act[e] @ wdT[e]^T ------------------------
// 256 thr (4 waves 2x2), M=128 N=128, K split 4-way. Both operands DMA'd.
__global__ __launch_bounds__(256, 2)
void k2_down(const unsigned short* __restrict__ act,   // [e][T][INT_] bf16
             const unsigned short* __restrict__ wdT,   // [e][1024][4096] bf16
             float* __restrict__ out)
{
  const int e   = blockIdx.z;
  const int cnt = g_cnt[e];
  const int mt  = blockIdx.y >> 2;
  const int ks4 = blockIdx.y & 3;
  const int t0  = mt * 128;
  if (t0 >= cnt) return;

  __shared__ char sA[128 * 128];       // (16 KB)
  __shared__ char sB[128 * 128];       // (16 KB)

  const int nt   = blockIdx.x;
  const int tid  = threadIdx.x;
  const int lane = tid & 63;
  const int wv   = tid >> 6;           // 0..3
  const int wm   = (wv >> 1) * 64;
  const int wn   = (wv & 1) * 64;
  const int n0   = nt * 128;

  const unsigned short* ab = act + (size_t)e * T_TOK * INT_;
  const unsigned short* wb = wdT + (size_t)e * HID * INT_ + (size_t)n0 * INT_;

  f32x4 acc[4][4];
  #pragma unroll
  for (int i = 0; i < 4; ++i)
    #pragma unroll
    for (int j = 0; j < 4; ++j) acc[i][j] = (f32x4){0.f, 0.f, 0.f, 0.f};

  const int drow  = lane >> 3;
  const int dchk8 = (((lane & 7) ^ drow) << 3);

  const int kbeg = ks4 * (INT_ / 4);

  for (int kt = kbeg; kt < kbeg + INT_ / 4; kt += 64) {
    #pragma unroll
    for (int s = 0; s < 4; ++s) {
      const int rb = (s * 4 + wv) * 8;
      GL16(ab + (size_t)(t0 + rb + drow) * INT_ + kt + dchk8, sA + rb * 128);
      GL16(wb + (size_t)(rb + drow) * INT_ + kt + dchk8, sB + rb * 128);
    }
    __syncthreads();
    #pragma unroll
    for (int ks = 0; ks < 2; ++ks) {
      const int kfb = ks * 64 + ((lane >> 4) << 4);
      short8 af[4], bf[4];
      #pragma unroll
      for (int i = 0; i < 4; ++i) {
        const int r = wm + i * 16 + (lane & 15);
        af[i] = *(const short8*)(sA + r * 128 + (kfb ^ ((r & 7) << 4)));
      }
      #pragma unroll
      for (int j = 0; j < 4; ++j) {
        const int r = wn + j * 16 + (lane & 15);
        bf[j] = *(const short8*)(sB + r * 128 + (kfb ^ ((r & 7) << 4)));
      }
      #pragma unroll
      for (int i = 0; i < 4; ++i)
        #pragma unroll
        for (int j = 0; j < 4; ++j)
          acc[i][j] = __builtin_amdgcn_mfma_f32_16x16x32_bf16(af[i], bf[j], acc[i][j], 0, 0, 0);
    }
    __syncthreads();
  }

  #pragma unroll
  for (int i = 0; i < 4; ++i) {
    #pragma unroll
    for (int r = 0; r < 4; ++r) {
      const int slot = t0 + wm + i * 16 + ((lane >> 4) << 2) + r;
      if (slot < cnt) {
        const int token = g_tok[e][slot];
        #pragma unroll
        for (int j = 0; j < 4; ++j) {
          const int col = n0 + wn + j * 16 + (lane & 15);
          atomicAdd(out + (size_t)token * HID + col, acc[i][j][r]);
        }
      }
    }
  }
}

extern "C" void kernel_launch(void* const* d_in, const int* in_sizes, int n_in,
                              void* d_out, int out_size, void* d_ws, size_t ws_size,
                              hipStream_t stream) {
  const float* x   = (const float*)d_in[0];
  const int*   idx = (const int*)d_in[1];
  const float* wgu = (const float*)d_in[2];
  const float* wd  = (const float*)d_in[3];
  float* out = (float*)d_out;

  // workspace layout (bytes):
  // act   @ 0          : 8*1024*4096*2 = 67,108,864
  // xb16  @ 67108864   : 1024*1024*2   =  2,097,152
  // wguT  @ 69206016   : 8*8192*1024*2 = 134,217,728
  // wdT   @ 203423744  : 8*1024*4096*2 = 67,108,864   (total ~258 MiB)
  char* ws = (char*)d_ws;
  unsigned short* act  = (unsigned short*)(ws);
  unsigned short* xb16 = (unsigned short*)(ws + 67108864);
  unsigned short* wguT = (unsigned short*)(ws + 69206016);
  unsigned short* wdT  = (unsigned short*)(ws + 203423744);

  hipMemsetAsync(d_out, 0, (size_t)out_size * sizeof(float), stream);

  k0_compact<<<1, 512, 0, stream>>>(idx);
  cvt_x<<<T_TOK * HID / (256 * 8), 256, 0, stream>>>(x, xb16);
  cvt_T<<<dim3(8192 / 64, 1024 / 64, NE), 256, 0, stream>>>(wgu, wguT, 1024, 8192);
  cvt_T<<<dim3(1024 / 64, 4096 / 64, NE), 256, 0, stream>>>(wd, wdT, 4096, 1024);

  dim3 g1(INT_ / 128, T_TOK / 256, NE);        // (32, 4, 8)
  k1_gateup<<<g1, dim3(512), 0, stream>>>(xb16, wguT, act);

  dim3 g2(HID / 128, (T_TOK / 128) * 4, NE);   // (8, 32, 8) — y = mt*4|ks
  k2_down<<<g2, dim3(256), 0, stream>>>(act, wdT, out);
}

// Round 11
// 362.724 us; speedup vs baseline: 1.1434x; 1.0102x over previous
//
#include <hip/hip_runtime.h>
#include <hip/hip_bf16.h>
#include <stdint.h>

#define T_TOK 1024
#define HID   1024
#define INT_  4096
#define NE    8

typedef __attribute__((ext_vector_type(4))) float f32x4;
typedef __attribute__((ext_vector_type(8))) short short8;

__device__ int g_tok[NE][T_TOK];
__device__ int g_cnt[NE];

__device__ __forceinline__ uint32_t pack2bf(float a, float b) {
  unsigned short ua = __builtin_bit_cast(unsigned short, (__bf16)a);
  unsigned short ub = __builtin_bit_cast(unsigned short, (__bf16)b);
  return (uint32_t)ua | ((uint32_t)ub << 16);
}

// global_load_lds: per-lane global src, wave-uniform LDS base (HW adds lane*16)
#define GL16(gsrc, ldst)                                                       \
  __builtin_amdgcn_global_load_lds(                                            \
      (const __attribute__((address_space(1))) void*)(gsrc),                   \
      (__attribute__((address_space(3))) void*)(ldst), 16, 0, 0)

// ---------------- Kernel 0: per-expert token compaction ---------------------
__global__ void k0_compact(const int* __restrict__ mask)  // [T_TOK][NE]
{
  const int w    = threadIdx.x >> 6;
  const int lane = threadIdx.x & 63;
  if (w >= NE) return;
  const unsigned long long ltmask = (1ull << lane) - 1ull;
  int base = 0;
  #pragma unroll
  for (int c = 0; c < T_TOK / 64; ++c) {
    const int t = c * 64 + lane;
    const bool pred = mask[t * NE + w] != 0;
    const unsigned long long bal = __ballot(pred);
    if (pred) g_tok[w][base + __popcll(bal & ltmask)] = t;
    base += __popcll(bal);
  }
  if (lane == 0) g_cnt[w] = base;
}

// ---------------- cvt_x: x f32 -> bf16 linear -------------------------------
__global__ void cvt_x(const float* __restrict__ xin, unsigned short* __restrict__ xout)
{
  const int i = (blockIdx.x * 256 + threadIdx.x) * 8;
  f32x4 a = *(const f32x4*)(xin + i);
  f32x4 b = *(const f32x4*)(xin + i + 4);
  uint4 u;
  u.x = pack2bf(a[0], a[1]); u.y = pack2bf(a[2], a[3]);
  u.z = pack2bf(b[0], b[1]); u.w = pack2bf(b[2], b[3]);
  *(uint4*)(xout + i) = u;
}

// ---------------- cvt_T: per-expert [R][C] f32 -> [C][R] bf16 ---------------
__global__ void cvt_T(const float* __restrict__ in, unsigned short* __restrict__ out,
                      int R, int C)
{
  __shared__ float tile[64][65];
  const int e  = blockIdx.z;
  const int c0 = blockIdx.x * 64;
  const int r0 = blockIdx.y * 64;
  const float*    ip = in  + (size_t)e * R * C;
  unsigned short* op = out + (size_t)e * R * C;
  const int t  = threadIdx.x;
  const int rr = t >> 4, c4 = (t & 15) * 4;
  #pragma unroll
  for (int s = 0; s < 4; ++s) {
    f32x4 v = *(const f32x4*)(ip + (size_t)(r0 + s * 16 + rr) * C + c0 + c4);
    tile[s * 16 + rr][c4 + 0] = v[0];
    tile[s * 16 + rr][c4 + 1] = v[1];
    tile[s * 16 + rr][c4 + 2] = v[2];
    tile[s * 16 + rr][c4 + 3] = v[3];
  }
  __syncthreads();
  const int c = t >> 2, rs = (t & 3) * 16;
  uint4 u0, u1;
  u0.x = pack2bf(tile[rs + 0][c],  tile[rs + 1][c]);
  u0.y = pack2bf(tile[rs + 2][c],  tile[rs + 3][c]);
  u0.z = pack2bf(tile[rs + 4][c],  tile[rs + 5][c]);
  u0.w = pack2bf(tile[rs + 6][c],  tile[rs + 7][c]);
  u1.x = pack2bf(tile[rs + 8][c],  tile[rs + 9][c]);
  u1.y = pack2bf(tile[rs + 10][c], tile[rs + 11][c]);
  u1.z = pack2bf(tile[rs + 12][c], tile[rs + 13][c]);
  u1.w = pack2bf(tile[rs + 14][c], tile[rs + 15][c]);
  unsigned short* orow = op + (size_t)(c0 + c) * R + r0 + rs;
  *(uint4*)(orow)     = u0;
  *(uint4*)(orow + 8) = u1;
}

// ---------------- Kernel 1: act[e,slot,i] = up * silu(gate) -----------------
// Pure-bf16, double-buffered global_load_lds with issue-early prefetch
// (T3-minimum 2-phase; GL16 has no dest regs so regalloc can't sink it).
// 512 thr (8 waves, 2m x 4n), M=256, N=128 (gate AND up). LDS 128 KB.
__global__ __launch_bounds__(512, 1)
void k1_gateup(const unsigned short* __restrict__ xb,    // [T][H] bf16
               const unsigned short* __restrict__ wguT,  // [e][8192][1024] bf16
               unsigned short* __restrict__ act)         // [e][T][INT_] bf16
{
  const int e   = blockIdx.z;
  const int cnt = g_cnt[e];
  const int mt  = blockIdx.y;
  const int t0  = mt * 256;
  if (t0 >= cnt) return;

  __shared__ char sA [2][256 * 128];   // 64 KB
  __shared__ char sBg[2][128 * 128];   // 32 KB
  __shared__ char sBu[2][128 * 128];   // 32 KB

  const int nt   = blockIdx.x;
  const int tid  = threadIdx.x;
  const int lane = tid & 63;
  const int wv   = tid >> 6;           // 0..7
  const int wm   = (wv >> 2) * 128;    // 0/128
  const int wn   = (wv & 3) * 32;      // 0/32/64/96
  const int n0   = nt * 128;

  const unsigned short* wg = wguT + (size_t)e * 8192 * HID + (size_t)n0 * HID;
  const unsigned short* wu = wg + (size_t)4096 * HID;

  f32x4 accg[8][2], accu[8][2];
  #pragma unroll
  for (int i = 0; i < 8; ++i)
    #pragma unroll
    for (int j = 0; j < 2; ++j) {
      accg[i][j] = (f32x4){0.f, 0.f, 0.f, 0.f};
      accu[i][j] = (f32x4){0.f, 0.f, 0.f, 0.f};
    }

  const int drow  = lane >> 3;                    // 0..7
  const int dchk8 = (((lane & 7) ^ drow) << 3);   // source-XOR chunk (rule #21)

  int tokA[4];
  #pragma unroll
  for (int s = 0; s < 4; ++s)
    tokA[s] = g_tok[e][t0 + (s * 8 + wv) * 8 + drow];

#define K1_STAGE(B, KT)                                                        \
  do {                                                                         \
    _Pragma("unroll")                                                          \
    for (int s_ = 0; s_ < 4; ++s_) {                                           \
      const int rb_ = (s_ * 8 + wv) * 8;                                       \
      GL16(xb + (size_t)tokA[s_] * HID + (KT) + dchk8, sA[B] + rb_ * 128);     \
    }                                                                          \
    _Pragma("unroll")                                                          \
    for (int s_ = 0; s_ < 2; ++s_) {                                           \
      const int rb_ = (s_ * 8 + wv) * 8;                                       \
      GL16(wg + (size_t)(rb_ + drow) * HID + (KT) + dchk8, sBg[B] + rb_ * 128);\
      GL16(wu + (size_t)(rb_ + drow) * HID + (KT) + dchk8, sBu[B] + rb_ * 128);\
    }                                                                          \
  } while (0)

  K1_STAGE(0, 0);
  __syncthreads();

  #pragma unroll 2
  for (int t = 0; t < 16; ++t) {
    const int cur = t & 1;
    if (t < 15) K1_STAGE((t + 1) & 1, (t + 1) * 64);   // issue-early prefetch
    #pragma unroll
    for (int ks = 0; ks < 2; ++ks) {
      const int kfb = ks * 64 + ((lane >> 4) << 4);
      short8 af[8], bg[2], bu[2];
      #pragma unroll
      for (int i = 0; i < 8; ++i) {
        const int r = wm + i * 16 + (lane & 15);
        af[i] = *(const short8*)(sA[cur] + r * 128 + (kfb ^ ((r & 7) << 4)));
      }
      #pragma unroll
      for (int j = 0; j < 2; ++j) {
        const int r = wn + j * 16 + (lane & 15);
        const int off = r * 128 + (kfb ^ ((r & 7) << 4));
        bg[j] = *(const short8*)(sBg[cur] + off);
        bu[j] = *(const short8*)(sBu[cur] + off);
      }
      #pragma unroll
      for (int i = 0; i < 8; ++i)
        #pragma unroll
        for (int j = 0; j < 2; ++j) {
          accg[i][j] = __builtin_amdgcn_mfma_f32_16x16x32_bf16(af[i], bg[j], accg[i][j], 0, 0, 0);
          accu[i][j] = __builtin_amdgcn_mfma_f32_16x16x32_bf16(af[i], bu[j], accu[i][j], 0, 0, 0);
        }
    }
    __syncthreads();   // drains vmcnt (prefetch landed) + all waves done reading cur
  }
#undef K1_STAGE

  unsigned short* ab = act + (size_t)e * T_TOK * INT_;
  #pragma unroll
  for (int i = 0; i < 8; ++i) {
    #pragma unroll
    for (int r = 0; r < 4; ++r) {
      const int slot = t0 + wm + i * 16 + ((lane >> 4) << 2) + r;
      if (slot < cnt) {
        #pragma unroll
        for (int j = 0; j < 2; ++j) {
          const int col = n0 + wn + j * 16 + (lane & 15);
          const float g = accg[i][j][r];
          const float u = accu[i][j][r];
          const float s = u * g / (1.f + __expf(-g));
          ab[(size_t)slot * INT_ + col] = __builtin_bit_cast(unsigned short, (__bf16)s);
        }
      }
    }
  }
}

// ---------------- Kernel 2: out += act[e] @ wdT[e]^T ------------------------
// 256 thr (4 waves 2x2), M=128 N=128, K split 4-way, double-buffered GL16.
__global__ __launch_bounds__(256, 2)
void k2_down(const unsigned short* __restrict__ act,   // [e][T][INT_] bf16
             const unsigned short* __restrict__ wdT,   // [e][1024][4096] bf16
             float* __restrict__ out)
{
  const int e   = blockIdx.z;
  const int cnt = g_cnt[e];
  const int mt  = blockIdx.y >> 2;
  const int ks4 = blockIdx.y & 3;
  const int t0  = mt * 128;
  if (t0 >= cnt) return;

  __shared__ char sA[2][128 * 128];    // 32 KB
  __shared__ char sB[2][128 * 128];    // 32 KB

  const int nt   = blockIdx.x;
  const int tid  = threadIdx.x;
  const int lane = tid & 63;
  const int wv   = tid >> 6;           // 0..3
  const int wm   = (wv >> 1) * 64;
  const int wn   = (wv & 1) * 64;
  const int n0   = nt * 128;

  const unsigned short* ab = act + (size_t)e * T_TOK * INT_;
  const unsigned short* wb = wdT + (size_t)e * HID * INT_ + (size_t)n0 * INT_;

  f32x4 acc[4][4];
  #pragma unroll
  for (int i = 0; i < 4; ++i)
    #pragma unroll
    for (int j = 0; j < 4; ++j) acc[i][j] = (f32x4){0.f, 0.f, 0.f, 0.f};

  const int drow  = lane >> 3;
  const int dchk8 = (((lane & 7) ^ drow) << 3);
  const int kbeg  = ks4 * (INT_ / 4);

#define K2_STAGE(B, KT)                                                        \
  do {                                                                         \
    _Pragma("unroll")                                                          \
    for (int s_ = 0; s_ < 4; ++s_) {                                           \
      const int rb_ = (s_ * 4 + wv) * 8;                                       \
      GL16(ab + (size_t)(t0 + rb_ + drow) * INT_ + (KT) + dchk8, sA[B] + rb_ * 128); \
      GL16(wb + (size_t)(rb_ + drow) * INT_ + (KT) + dchk8, sB[B] + rb_ * 128);      \
    }                                                                          \
  } while (0)

  K2_STAGE(0, kbeg);
  __syncthreads();

  #pragma unroll 2
  for (int t = 0; t < 16; ++t) {
    const int cur = t & 1;
    if (t < 15) K2_STAGE((t + 1) & 1, kbeg + (t + 1) * 64);
    #pragma unroll
    for (int ks = 0; ks < 2; ++ks) {
      const int kfb = ks * 64 + ((lane >> 4) << 4);
      short8 af[4], bf[4];
      #pragma unroll
      for (int i = 0; i < 4; ++i) {
        const int r = wm + i * 16 + (lane & 15);
        af[i] = *(const short8*)(sA[cur] + r * 128 + (kfb ^ ((r & 7) << 4)));
      }
      #pragma unroll
      for (int j = 0; j < 4; ++j) {
        const int r = wn + j * 16 + (lane & 15);
        bf[j] = *(const short8*)(sB[cur] + r * 128 + (kfb ^ ((r & 7) << 4)));
      }
      #pragma unroll
      for (int i = 0; i < 4; ++i)
        #pragma unroll
        for (int j = 0; j < 4; ++j)
          acc[i][j] = __builtin_amdgcn_mfma_f32_16x16x32_bf16(af[i], bf[j], acc[i][j], 0, 0, 0);
    }
    __syncthreads();
  }
#undef K2_STAGE

  #pragma unroll
  for (int i = 0; i < 4; ++i) {
    #pragma unroll
    for (int r = 0; r < 4; ++r) {
      const int slot = t0 + wm + i * 16 + ((lane >> 4) << 2) + r;
      if (slot < cnt) {
        const int token = g_tok[e][slot];
        #pragma unroll
        for (int j = 0; j < 4; ++j) {
          const int col = n0 + wn + j * 16 + (lane & 15);
          atomicAdd(out + (size_t)token * HID + col, acc[i][j][r]);
        }
      }
    }
  }
}

extern "C" void kernel_launch(void* const* d_in, const int* in_sizes, int n_in,
                              void* d_out, int out_size, void* d_ws, size_t ws_size,
                              hipStream_t stream) {
  const float* x   = (const float*)d_in[0];
  const int*   idx = (const int*)d_in[1];
  const float* wgu = (const float*)d_in[2];
  const float* wd  = (const float*)d_in[3];
  float* out = (float*)d_out;

  // workspace layout (bytes):
  // act   @ 0          : 67,108,864
  // xb16  @ 67108864   :  2,097,152
  // wguT  @ 69206016   : 134,217,728
  // wdT   @ 203423744  : 67,108,864   (total ~258 MiB)
  char* ws = (char*)d_ws;
  unsigned short* act  = (unsigned short*)(ws);
  unsigned short* xb16 = (unsigned short*)(ws + 67108864);
  unsigned short* wguT = (unsigned short*)(ws + 69206016);
  unsigned short* wdT  = (unsigned short*)(ws + 203423744);

  hipMemsetAsync(d_out, 0, (size_t)out_size * sizeof(float), stream);

  k0_compact<<<1, 512, 0, stream>>>(idx);
  cvt_x<<<T_TOK * HID / (256 * 8), 256, 0, stream>>>(x, xb16);
  cvt_T<<<dim3(8192 / 64, 1024 / 64, NE), 256, 0, stream>>>(wgu, wguT, 1024, 8192);
  cvt_T<<<dim3(1024 / 64, 4096 / 64, NE), 256, 0, stream>>>(wd, wdT, 4096, 1024);

  dim3 g1(INT_ / 128, T_TOK / 256, NE);        // (32, 4, 8)
  k1_gateup<<<g1, dim3(512), 0, stream>>>(xb16, wguT, act);

  dim3 g2(HID / 128, (T_TOK / 128) * 4, NE);   // (8, 32, 8) — y = mt*4|ks
  k2_down<<<g2, dim3(256), 0, stream>>>(act, wdT, out);
}

// Round 12
// 346.135 us; speedup vs baseline: 1.1982x; 1.0479x over previous
//
#include <hip/hip_runtime.h>
#include <hip/hip_bf16.h>
#include <stdint.h>

#define T_TOK 1024
#define HID   1024
#define INT_  4096
#define NE    8

typedef __attribute__((ext_vector_type(4))) float f32x4;
typedef __attribute__((ext_vector_type(8))) short short8;

__device__ int g_tok[NE][T_TOK];
__device__ int g_cnt[NE];

__device__ __forceinline__ uint32_t pack2bf(float a, float b) {
  unsigned short ua = __builtin_bit_cast(unsigned short, (__bf16)a);
  unsigned short ub = __builtin_bit_cast(unsigned short, (__bf16)b);
  return (uint32_t)ua | ((uint32_t)ub << 16);
}

// global_load_lds: per-lane global src, wave-uniform LDS base (HW adds lane*16)
#define GL16(gsrc, ldst)                                                       \
  __builtin_amdgcn_global_load_lds(                                            \
      (const __attribute__((address_space(1))) void*)(gsrc),                   \
      (__attribute__((address_space(3))) void*)(ldst), 16, 0, 0)

// ---------------- Kernel 0: per-expert token compaction ---------------------
__global__ void k0_compact(const int* __restrict__ mask)  // [T_TOK][NE]
{
  const int w    = threadIdx.x >> 6;
  const int lane = threadIdx.x & 63;
  if (w >= NE) return;
  const unsigned long long ltmask = (1ull << lane) - 1ull;
  int base = 0;
  #pragma unroll
  for (int c = 0; c < T_TOK / 64; ++c) {
    const int t = c * 64 + lane;
    const bool pred = mask[t * NE + w] != 0;
    const unsigned long long bal = __ballot(pred);
    if (pred) g_tok[w][base + __popcll(bal & ltmask)] = t;
    base += __popcll(bal);
  }
  if (lane == 0) g_cnt[w] = base;
}

// ---------------- cvt_x: x f32 -> bf16 linear -------------------------------
__global__ void cvt_x(const float* __restrict__ xin, unsigned short* __restrict__ xout)
{
  const int i = (blockIdx.x * 256 + threadIdx.x) * 8;
  f32x4 a = *(const f32x4*)(xin + i);
  f32x4 b = *(const f32x4*)(xin + i + 4);
  uint4 u;
  u.x = pack2bf(a[0], a[1]); u.y = pack2bf(a[2], a[3]);
  u.z = pack2bf(b[0], b[1]); u.w = pack2bf(b[2], b[3]);
  *(uint4*)(xout + i) = u;
}

// ---------------- cvt_T: per-expert [R][C] f32 -> [C][R] bf16 ---------------
__global__ void cvt_T(const float* __restrict__ in, unsigned short* __restrict__ out,
                      int R, int C)
{
  __shared__ float tile[64][65];
  const int e  = blockIdx.z;
  const int c0 = blockIdx.x * 64;
  const int r0 = blockIdx.y * 64;
  const float*    ip = in  + (size_t)e * R * C;
  unsigned short* op = out + (size_t)e * R * C;
  const int t  = threadIdx.x;
  const int rr = t >> 4, c4 = (t & 15) * 4;
  #pragma unroll
  for (int s = 0; s < 4; ++s) {
    f32x4 v = *(const f32x4*)(ip + (size_t)(r0 + s * 16 + rr) * C + c0 + c4);
    tile[s * 16 + rr][c4 + 0] = v[0];
    tile[s * 16 + rr][c4 + 1] = v[1];
    tile[s * 16 + rr][c4 + 2] = v[2];
    tile[s * 16 + rr][c4 + 3] = v[3];
  }
  __syncthreads();
  const int c = t >> 2, rs = (t & 3) * 16;
  uint4 u0, u1;
  u0.x = pack2bf(tile[rs + 0][c],  tile[rs + 1][c]);
  u0.y = pack2bf(tile[rs + 2][c],  tile[rs + 3][c]);
  u0.z = pack2bf(tile[rs + 4][c],  tile[rs + 5][c]);
  u0.w = pack2bf(tile[rs + 6][c],  tile[rs + 7][c]);
  u1.x = pack2bf(tile[rs + 8][c],  tile[rs + 9][c]);
  u1.y = pack2bf(tile[rs + 10][c], tile[rs + 11][c]);
  u1.z = pack2bf(tile[rs + 12][c], tile[rs + 13][c]);
  u1.w = pack2bf(tile[rs + 14][c], tile[rs + 15][c]);
  unsigned short* orow = op + (size_t)(c0 + c) * R + r0 + rs;
  *(uint4*)(orow)     = u0;
  *(uint4*)(orow + 8) = u1;
}

// ---------------- Kernel 1: act[e,slot,i] = up * silu(gate) -----------------
// 3-deep GL16 pipeline, counted vmcnt (never drains mid-loop), raw barriers.
// 512 thr (8 waves, 4m x 2n). M=256, N=64 (gate AND up). LDS 144 KB.
// 6 GL16/thread/stage -> steady-state vmcnt(12) = 2 tiles in flight.
__global__ __launch_bounds__(512, 1)
void k1_gateup(const unsigned short* __restrict__ xb,    // [T][H] bf16
               const unsigned short* __restrict__ wguT,  // [e][8192][1024] bf16
               unsigned short* __restrict__ act)         // [e][T][INT_] bf16
{
  const int e   = blockIdx.z;
  const int cnt = g_cnt[e];
  const int mt  = blockIdx.y;
  const int t0  = mt * 256;
  if (t0 >= cnt) return;

  __shared__ char sA [3][256 * 128];   // 96 KB
  __shared__ char sBg[3][64 * 128];    // 24 KB
  __shared__ char sBu[3][64 * 128];    // 24 KB

  const int nt   = blockIdx.x;         // 0..63
  const int tid  = threadIdx.x;
  const int lane = tid & 63;
  const int wv   = tid >> 6;           // 0..7
  const int wm   = (wv >> 1) * 64;     // 0/64/128/192
  const int wn   = (wv & 1) * 32;      // 0/32
  const int n0   = nt * 64;

  const unsigned short* wg = wguT + (size_t)e * 8192 * HID + (size_t)n0 * HID;
  const unsigned short* wu = wg + (size_t)4096 * HID;

  f32x4 accg[4][2], accu[4][2];
  #pragma unroll
  for (int i = 0; i < 4; ++i)
    #pragma unroll
    for (int j = 0; j < 2; ++j) {
      accg[i][j] = (f32x4){0.f, 0.f, 0.f, 0.f};
      accu[i][j] = (f32x4){0.f, 0.f, 0.f, 0.f};
    }

  const int drow  = lane >> 3;                    // 0..7
  const int dchk8 = (((lane & 7) ^ drow) << 3);   // source-XOR chunk (rule #21)

  int tokA[4];
  #pragma unroll
  for (int s = 0; s < 4; ++s)
    tokA[s] = g_tok[e][t0 + (s * 8 + wv) * 8 + drow];

#define K1_STAGE(B, T_)                                                        \
  do {                                                                         \
    const int kt_ = (T_) * 64;                                                 \
    _Pragma("unroll")                                                          \
    for (int s_ = 0; s_ < 4; ++s_) {                                           \
      const int rb_ = (s_ * 8 + wv) * 8;                                       \
      GL16(xb + (size_t)tokA[s_] * HID + kt_ + dchk8, sA[B] + rb_ * 128);      \
    }                                                                          \
    {                                                                          \
      const int rb_ = wv * 8;                                                  \
      GL16(wg + (size_t)(rb_ + drow) * HID + kt_ + dchk8, sBg[B] + rb_ * 128); \
      GL16(wu + (size_t)(rb_ + drow) * HID + kt_ + dchk8, sBu[B] + rb_ * 128); \
    }                                                                          \
  } while (0)

  K1_STAGE(0, 0);
  K1_STAGE(1, 1);

  #pragma unroll
  for (int t = 0; t < 16; ++t) {
    if (t + 2 < 16) K1_STAGE((t + 2) % 3, t + 2);
    if (t < 14)      asm volatile("s_waitcnt vmcnt(12)" ::: "memory");
    else if (t == 14) asm volatile("s_waitcnt vmcnt(6)" ::: "memory");
    else              asm volatile("s_waitcnt vmcnt(0)" ::: "memory");
    __builtin_amdgcn_s_barrier();
    __builtin_amdgcn_sched_barrier(0);   // pin ds_reads below the barrier
    const char* cA  = sA [t % 3];
    const char* cBg = sBg[t % 3];
    const char* cBu = sBu[t % 3];
    #pragma unroll
    for (int ks = 0; ks < 2; ++ks) {
      const int kfb = ks * 64 + ((lane >> 4) << 4);
      short8 af[4], bg[2], bu[2];
      #pragma unroll
      for (int i = 0; i < 4; ++i) {
        const int r = wm + i * 16 + (lane & 15);
        af[i] = *(const short8*)(cA + r * 128 + (kfb ^ ((r & 7) << 4)));
      }
      #pragma unroll
      for (int j = 0; j < 2; ++j) {
        const int r = wn + j * 16 + (lane & 15);
        const int off = r * 128 + (kfb ^ ((r & 7) << 4));
        bg[j] = *(const short8*)(cBg + off);
        bu[j] = *(const short8*)(cBu + off);
      }
      #pragma unroll
      for (int i = 0; i < 4; ++i)
        #pragma unroll
        for (int j = 0; j < 2; ++j) {
          accg[i][j] = __builtin_amdgcn_mfma_f32_16x16x32_bf16(af[i], bg[j], accg[i][j], 0, 0, 0);
          accu[i][j] = __builtin_amdgcn_mfma_f32_16x16x32_bf16(af[i], bu[j], accu[i][j], 0, 0, 0);
        }
    }
    __builtin_amdgcn_s_barrier();        // protect buf (re-staged next iter)
  }
#undef K1_STAGE

  unsigned short* ab = act + (size_t)e * T_TOK * INT_;
  #pragma unroll
  for (int i = 0; i < 4; ++i) {
    #pragma unroll
    for (int r = 0; r < 4; ++r) {
      const int slot = t0 + wm + i * 16 + ((lane >> 4) << 2) + r;
      if (slot < cnt) {
        #pragma unroll
        for (int j = 0; j < 2; ++j) {
          const int col = n0 + wn + j * 16 + (lane & 15);
          const float g = accg[i][j][r];
          const float u = accu[i][j][r];
          const float s = u * g / (1.f + __expf(-g));
          ab[(size_t)slot * INT_ + col] = __builtin_bit_cast(unsigned short, (__bf16)s);
        }
      }
    }
  }
}

// ---------------- Kernel 2: out += act[e] @ wdT[e]^T ------------------------
// 256 thr (4 waves 2x2), M=128 N=128, K split 4-way, 2-buf counted vmcnt(8).
__global__ __launch_bounds__(256, 2)
void k2_down(const unsigned short* __restrict__ act,   // [e][T][INT_] bf16
             const unsigned short* __restrict__ wdT,   // [e][1024][4096] bf16
             float* __restrict__ out)
{
  const int e   = blockIdx.z;
  const int cnt = g_cnt[e];
  const int mt  = blockIdx.y >> 2;
  const int ks4 = blockIdx.y & 3;
  const int t0  = mt * 128;
  if (t0 >= cnt) return;

  __shared__ char sA[2][128 * 128];    // 32 KB
  __shared__ char sB[2][128 * 128];    // 32 KB

  const int nt   = blockIdx.x;
  const int tid  = threadIdx.x;
  const int lane = tid & 63;
  const int wv   = tid >> 6;           // 0..3
  const int wm   = (wv >> 1) * 64;
  const int wn   = (wv & 1) * 64;
  const int n0   = nt * 128;

  const unsigned short* ab = act + (size_t)e * T_TOK * INT_;
  const unsigned short* wb = wdT + (size_t)e * HID * INT_ + (size_t)n0 * INT_;

  f32x4 acc[4][4];
  #pragma unroll
  for (int i = 0; i < 4; ++i)
    #pragma unroll
    for (int j = 0; j < 4; ++j) acc[i][j] = (f32x4){0.f, 0.f, 0.f, 0.f};

  const int drow  = lane >> 3;
  const int dchk8 = (((lane & 7) ^ drow) << 3);
  const int kbeg  = ks4 * (INT_ / 4);

#define K2_STAGE(B, KT)                                                        \
  do {                                                                         \
    _Pragma("unroll")                                                          \
    for (int s_ = 0; s_ < 4; ++s_) {                                           \
      const int rb_ = (s_ * 4 + wv) * 8;                                       \
      GL16(ab + (size_t)(t0 + rb_ + drow) * INT_ + (KT) + dchk8, sA[B] + rb_ * 128); \
      GL16(wb + (size_t)(rb_ + drow) * INT_ + (KT) + dchk8, sB[B] + rb_ * 128);      \
    }                                                                          \
  } while (0)

  K2_STAGE(0, kbeg);

  #pragma unroll
  for (int t = 0; t < 16; ++t) {
    const int cur = t & 1;
    if (t < 15) K2_STAGE(cur ^ 1, kbeg + (t + 1) * 64);
    if (t < 15) asm volatile("s_waitcnt vmcnt(8)" ::: "memory");
    else        asm volatile("s_waitcnt vmcnt(0)" ::: "memory");
    __builtin_amdgcn_s_barrier();
    __builtin_amdgcn_sched_barrier(0);
    #pragma unroll
    for (int ks = 0; ks < 2; ++ks) {
      const int kfb = ks * 64 + ((lane >> 4) << 4);
      short8 af[4], bf[4];
      #pragma unroll
      for (int i = 0; i < 4; ++i) {
        const int r = wm + i * 16 + (lane & 15);
        af[i] = *(const short8*)(sA[cur] + r * 128 + (kfb ^ ((r & 7) << 4)));
      }
      #pragma unroll
      for (int j = 0; j < 4; ++j) {
        const int r = wn + j * 16 + (lane & 15);
        bf[j] = *(const short8*)(sB[cur] + r * 128 + (kfb ^ ((r & 7) << 4)));
      }
      #pragma unroll
      for (int i = 0; i < 4; ++i)
        #pragma unroll
        for (int j = 0; j < 4; ++j)
          acc[i][j] = __builtin_amdgcn_mfma_f32_16x16x32_bf16(af[i], bf[j], acc[i][j], 0, 0, 0);
    }
    __builtin_amdgcn_s_barrier();
  }
#undef K2_STAGE

  #pragma unroll
  for (int i = 0; i < 4; ++i) {
    #pragma unroll
    for (int r = 0; r < 4; ++r) {
      const int slot = t0 + wm + i * 16 + ((lane >> 4) << 2) + r;
      if (slot < cnt) {
        const int token = g_tok[e][slot];
        #pragma unroll
        for (int j = 0; j < 4; ++j) {
          const int col = n0 + wn + j * 16 + (lane & 15);
          atomicAdd(out + (size_t)token * HID + col, acc[i][j][r]);
        }
      }
    }
  }
}

extern "C" void kernel_launch(void* const* d_in, const int* in_sizes, int n_in,
                              void* d_out, int out_size, void* d_ws, size_t ws_size,
                              hipStream_t stream) {
  const float* x   = (const float*)d_in[0];
  const int*   idx = (const int*)d_in[1];
  const float* wgu = (const float*)d_in[2];
  const float* wd  = (const float*)d_in[3];
  float* out = (float*)d_out;

  // workspace layout (bytes):
  // act   @ 0          : 67,108,864
  // xb16  @ 67108864   :  2,097,152
  // wguT  @ 69206016   : 134,217,728
  // wdT   @ 203423744  : 67,108,864   (total ~258 MiB)
  char* ws = (char*)d_ws;
  unsigned short* act  = (unsigned short*)(ws);
  unsigned short* xb16 = (unsigned short*)(ws + 67108864);
  unsigned short* wguT = (unsigned short*)(ws + 69206016);
  unsigned short* wdT  = (unsigned short*)(ws + 203423744);

  hipMemsetAsync(d_out, 0, (size_t)out_size * sizeof(float), stream);

  k0_compact<<<1, 512, 0, stream>>>(idx);
  cvt_x<<<T_TOK * HID / (256 * 8), 256, 0, stream>>>(x, xb16);
  cvt_T<<<dim3(8192 / 64, 1024 / 64, NE), 256, 0, stream>>>(wgu, wguT, 1024, 8192);
  cvt_T<<<dim3(1024 / 64, 4096 / 64, NE), 256, 0, stream>>>(wd, wdT, 4096, 1024);

  dim3 g1(INT_ / 64, T_TOK / 256, NE);         // (64, 4, 8)
  k1_gateup<<<g1, dim3(512), 0, stream>>>(xb16, wguT, act);

  dim3 g2(HID / 128, (T_TOK / 128) * 4, NE);   // (8, 32, 8) — y = mt*4|ks
  k2_down<<<g2, dim3(256), 0, stream>>>(act, wdT, out);
}